// Round 4
// baseline (60.162 us; speedup 1.0000x reference)
//
#include <hip/hip_runtime.h>
#include <stdint.h>

#define B_DIM 2048
#define K_DIM 2048
#define N_PACK 4096

typedef int v4i __attribute__((ext_vector_type(4)));

__device__ __forceinline__ float fqf(float x) {
    float q = rintf(x * 32.0f);
    q = fminf(fmaxf(q, -128.0f), 127.0f);
    return q * 0.03125f;
}
__device__ __forceinline__ int q8i(float x) {
    float q = rintf(x * 32.0f);
    q = fminf(fmaxf(q, -128.0f), 127.0f);
    return (int)q;
}
__device__ __forceinline__ float fsigm(float x) {
    return __fdividef(1.0f, 1.0f + __expf(-x));
}
__device__ __forceinline__ float ftanh(float x) {
    return __fdividef(2.0f, 1.0f + __expf(-2.0f * x)) - 1.0f;
}

// One kernel quantizes everything (R8-proven version, at HBM roofline):
//  blocks [0, 2048)        : Xh rows  -> Xhq[m][k] int8, k<1024 from X, else h
//  blocks [2048, 6144)     : W rows   -> Wq[p][k] int8, packed p = j*4 + gate
//  block  6144             : bias     -> bqp[j*4 + gate] (fake-quantized f32)
__global__ __launch_bounds__(256) void quant_pack(
    const float* __restrict__ X, const float* __restrict__ hI,
    const float* __restrict__ W, const float* __restrict__ bias,
    int8_t* __restrict__ Xhq, int8_t* __restrict__ Wq, float* __restrict__ bqp)
{
    const int bid = blockIdx.x;
    const int t = threadIdx.x;
    if (bid < B_DIM) {
        const int m = bid;
        const int k0 = t * 8;
        const float* src = (k0 < 1024) ? (X + (size_t)m * 1024 + k0)
                                       : (hI + (size_t)m * 1024 + (k0 - 1024));
        float4 v0 = *(const float4*)src;
        float4 v1 = *(const float4*)(src + 4);
        union { int8_t c[8]; int64_t ll; } u;
        u.c[0] = (int8_t)q8i(v0.x); u.c[1] = (int8_t)q8i(v0.y);
        u.c[2] = (int8_t)q8i(v0.z); u.c[3] = (int8_t)q8i(v0.w);
        u.c[4] = (int8_t)q8i(v1.x); u.c[5] = (int8_t)q8i(v1.y);
        u.c[6] = (int8_t)q8i(v1.z); u.c[7] = (int8_t)q8i(v1.w);
        *(int64_t*)(Xhq + (size_t)m * K_DIM + k0) = u.ll;
    } else if (bid < B_DIM + N_PACK) {
        const int r = bid - B_DIM;          // original weight row (gate*1024 + j)
        const int gate = r >> 10, j = r & 1023;
        const int p = (j << 2) | gate;      // packed row
        const int k0 = t * 8;
        const float* src = W + (size_t)r * K_DIM + k0;
        float4 v0 = *(const float4*)src;
        float4 v1 = *(const float4*)(src + 4);
        union { int8_t c[8]; int64_t ll; } u;
        u.c[0] = (int8_t)q8i(v0.x); u.c[1] = (int8_t)q8i(v0.y);
        u.c[2] = (int8_t)q8i(v0.z); u.c[3] = (int8_t)q8i(v0.w);
        u.c[4] = (int8_t)q8i(v1.x); u.c[5] = (int8_t)q8i(v1.y);
        u.c[6] = (int8_t)q8i(v1.z); u.c[7] = (int8_t)q8i(v1.w);
        *(int64_t*)(Wq + (size_t)p * K_DIM + k0) = u.ll;
    } else {
        for (int idx = t; idx < N_PACK; idx += 256) {
            const int gate = idx >> 10, j = idx & 1023;
            bqp[(j << 2) | gate] = fqf(bias[idx]);
        }
    }
}

// GEMM C[2048][4096p] = Xhq @ Wq^T (int8 -> i32, exact), fused LSTM epilogue.
// R12: attack the measured 2-phase stall structure (R8/R11 both ~3.4x MFMA
// floor; LDS cut in R11 changed nothing -> sync-bound, not data-bound).
//   ONE barrier per K-tile (16 total vs R8's 32), 3-slot LDS, depth-2
//   counted prefetch: iteration kt waits vmcnt(6) for loads issued TWO
//   iterations ago, then {barrier | STAGE(kt+2) | ds_read slot kt%3 |
//   setprio(1) 32-MFMA setprio(0)}. No trailing barrier: slot (kt+2)%3 =
//   (kt-1)%3's readers all sampled LDS before barrier(kt) (each ds_read is
//   consumed by a pre-barrier MFMA whose lgkmcnt wait forces completion).
//   Geometry: BM=128, BN=256 -> grid 256 = 1 block/CU (single dispatch
//   round), 8 waves (2m x 4n), 64x64 wave tiles, acc[4][4]; per-SIMD MFMA
//   between barriers = 1300 cyc (R9's failed phase attempt had 160).
// XCD swizzle (R10 map): xcd=b&7 owns 8mt x 4nt -> 2MB A + 2MB B = one L2.
// LDS chunk swizzle (proven 0-conflict): LDS[r][s] holds chunk s ^ (r&7),
// via pre-swizzled global source (linear gll dest, m104 rule).
__global__ __launch_bounds__(512, 1) void lstm_gemm(
    const int8_t* __restrict__ Xhq, const int8_t* __restrict__ Wq,
    const float* __restrict__ bqp, const float* __restrict__ cin,
    float* __restrict__ hout, float* __restrict__ cout_)
{
    __shared__ __align__(16) char raw[147456];  // 3 x (A 16K + B 32K); epilogue aliases
    const int t = threadIdx.x;          // 0..511
    const int l = t & 63;
    const int wave = t >> 6;            // 0..7
    const int wm = wave >> 2;           // 0..1  (64 m-rows each)
    const int wn = wave & 3;            // 0..3  (64 packed cols each)

    // XCD-aware remap: 256 blocks = 8 xcd x 32 slot (bijective)
    const int b = blockIdx.x;
    const int xcd = b & 7;
    const int slot = b >> 3;            // 0..31
    const int mt = ((xcd & 1) << 3) + (slot & 7);    // 0..15
    const int nt = ((xcd >> 1) << 2) + (slot >> 3);  // 0..15
    const int m0 = mt * 128;
    const int n0 = nt * 256;

    v4i acc[4][4];
    #pragma unroll
    for (int i = 0; i < 4; ++i)
        #pragma unroll
        for (int j = 0; j < 4; ++j)
            acc[i][j] = (v4i)0;

    // staging: thread t covers rows {srow + 64*i}, chunk-slot t&7.
    // LDS slot (r, s) holds global chunk s ^ (r&7); (srow+64i)&7 == srow&7.
    const int srow = t >> 3;                      // 0..63
    const int schunk = (t & 7) ^ (srow & 7);
    const int8_t* gA = Xhq + (size_t)(m0 + srow) * K_DIM + schunk * 16;
    const int8_t* gB = Wq  + (size_t)(n0 + srow) * K_DIM + schunk * 16;

    // slot sb: A = 128 rows x 128B (16 KB) at +0, B = 256 rows x 128B (32 KB)
    // at +16384. 6 gll per thread per tile.
#define STAGE(sb, kt) do { \
    char* Ad_ = raw + (sb); \
    char* Bd_ = raw + (sb) + 16384; \
    _Pragma("unroll") \
    for (int i_ = 0; i_ < 2; ++i_) \
        __builtin_amdgcn_global_load_lds( \
            (const __attribute__((address_space(1))) uint32_t*)(gA + (size_t)(i_ * 64) * K_DIM + (kt) * 128), \
            (__attribute__((address_space(3))) uint32_t*)(Ad_ + i_ * 8192 + t * 16), 16, 0, 0); \
    _Pragma("unroll") \
    for (int i_ = 0; i_ < 4; ++i_) \
        __builtin_amdgcn_global_load_lds( \
            (const __attribute__((address_space(1))) uint32_t*)(gB + (size_t)(i_ * 64) * K_DIM + (kt) * 128), \
            (__attribute__((address_space(3))) uint32_t*)(Bd_ + i_ * 8192 + t * 16), 16, 0, 0); \
} while (0)

    // Prologue: tile0 -> slot0, tile1 -> slot1 (12 loads in flight).
    STAGE(0, 0);
    STAGE(49152, 1);

    const int rrow = l & 15;
    const int lx = l & 7;   // == r&7 for all fragment rows
    const int g4 = l >> 4;  // 0..3

    int sCur = 0;           // byte base of slot kt%3
    int sNxt = 98304;       // byte base of slot (kt+2)%3
    for (int kt = 0; kt < 16; ++kt) {
        // Wait: tile kt landed. Outstanding newer = tile kt+1's 6 loads
        // (tile kt+2 not yet issued). Per-wave vmcnt + barrier => all waves'
        // tile-kt loads are in LDS before anyone reads.
        if (kt < 15) asm volatile("s_waitcnt vmcnt(6)" ::: "memory");
        else         asm volatile("s_waitcnt vmcnt(0)" ::: "memory");
        asm volatile("s_barrier" ::: "memory");
        // Stage tile kt+2 into slot (kt-1)%3: its readers (iter kt-1) all
        // sampled LDS before barrier(kt) -- safe without a trailing barrier.
        if (kt < 14) STAGE(sNxt, kt + 2);

        const char* As = raw + sCur;
        const char* Bs = As + 16384;
        v4i a[2][4], b2[2][4];
        #pragma unroll
        for (int kk = 0; kk < 2; ++kk) {
            const int sl = ((kk * 4 + g4) ^ lx) * 16;
            #pragma unroll
            for (int mf = 0; mf < 4; ++mf)
                a[kk][mf] = *(const v4i*)(As + (wm * 64 + mf * 16 + rrow) * 128 + sl);
            #pragma unroll
            for (int nf = 0; nf < 4; ++nf)
                b2[kk][nf] = *(const v4i*)(Bs + (wn * 64 + nf * 16 + rrow) * 128 + sl);
        }
        __builtin_amdgcn_s_setprio(1);
        #pragma unroll
        for (int kk = 0; kk < 2; ++kk)
            #pragma unroll
            for (int mf = 0; mf < 4; ++mf)
                #pragma unroll
                for (int nf = 0; nf < 4; ++nf)
                    acc[mf][nf] = __builtin_amdgcn_mfma_i32_16x16x64_i8(
                        a[kk][mf], b2[kk][nf], acc[mf][nf], 0, 0, 0);
        __builtin_amdgcn_s_setprio(0);

        sCur += 49152; if (sCur == 147456) sCur = 0;
        sNxt += 49152; if (sNxt == 147456) sNxt = 0;
    }

#undef STAGE

    // Epilogue (R10-verified for this exact geometry): four 32-row quarters
    // through an LDS C-tile. Quarter q rows [q*32,+32): wm = q>>1, mf=(q&1)*2+{0,1}.
    float (*Cs)[264] = (float(*)[264])raw;   // [32][264] f32 = 33792 B
    const float sc = 0.0009765625f;          // 2^-10
    for (int q = 0; q < 4; ++q) {
        __syncthreads();
        if (wm == (q >> 1)) {
            #pragma unroll
            for (int mf2 = 0; mf2 < 2; ++mf2) {
                const int mf = (q & 1) * 2 + mf2;
                const int rb = mf2 * 16 + ((l >> 4) << 2);
                #pragma unroll
                for (int nf = 0; nf < 4; ++nf) {
                    const int col = wn * 64 + nf * 16 + (l & 15);
                    #pragma unroll
                    for (int rr = 0; rr < 4; ++rr)
                        Cs[rb + rr][col] = (float)acc[mf][nf][rr] * sc;
                }
            }
        }
        __syncthreads();
        #pragma unroll
        for (int it = 0; it < 4; ++it) {
            const int idx = it * 512 + t;        // 0..2047 = 32 rows x 64 j
            const int row = idx >> 6;
            const int jl = idx & 63;
            float4 y = *(const float4*)&Cs[row][jl << 2];
            float4 bv = *(const float4*)&bqp[n0 + (jl << 2)];
            const int m = m0 + q * 32 + row;
            const int j = (n0 >> 2) + jl;
            const float ig = fqf(fsigm(y.x + bv.x));
            const float fg = fqf(fsigm(y.y + bv.y));
            const float gg = fqf(ftanh(y.z + bv.z));
            const float og = fqf(fsigm(y.w + bv.w));
            const float cq = fqf(cin[(size_t)m * 1024 + j]);
            const float cn = cq * fg + ig * gg;
            const float hn = fqf(ftanh(cn)) * og;
            hout[(size_t)m * 1024 + j] = hn;
            cout_[(size_t)m * 1024 + j] = cn;
        }
    }
}

extern "C" void kernel_launch(void* const* d_in, const int* in_sizes, int n_in,
                              void* d_out, int out_size, void* d_ws, size_t ws_size,
                              hipStream_t stream) {
    const float* X    = (const float*)d_in[0];   // [2048,1024]
    const float* h    = (const float*)d_in[1];   // [2048,1024]
    const float* c    = (const float*)d_in[2];   // [2048,1024]
    const float* W    = (const float*)d_in[3];   // [4096,2048]
    const float* bias = (const float*)d_in[4];   // [4096]

    float* out   = (float*)d_out;
    float* h_out = out;                          // [2048,1024]
    float* c_out = out + (size_t)B_DIM * 1024;   // [2048,1024]

    char* ws = (char*)d_ws;
    int8_t* Xhq = (int8_t*)ws;                              // 4 MB
    int8_t* Wq  = (int8_t*)(ws + (size_t)4 * 1024 * 1024);  // 8 MB
    float*  bqp = (float*)(ws + (size_t)12 * 1024 * 1024);  // 16 KB

    quant_pack<<<B_DIM + N_PACK + 1, 256, 0, stream>>>(X, h, W, bias, Xhq, Wq, bqp);

    lstm_gemm<<<256, 512, 0, stream>>>(Xhq, Wq, bqp, c, h_out, c_out);
}

// Round 5
// 42.151 us; speedup vs baseline: 1.4273x; 1.4273x over previous
//
#include <hip/hip_runtime.h>
#include <stdint.h>

#define B_DIM 2048
#define K_DIM 2048
#define N_PACK 4096

typedef int v4i __attribute__((ext_vector_type(4)));

__device__ __forceinline__ float fqf(float x) {
    float q = rintf(x * 32.0f);
    q = fminf(fmaxf(q, -128.0f), 127.0f);
    return q * 0.03125f;
}
__device__ __forceinline__ int q8i(float x) {
    float q = rintf(x * 32.0f);
    q = fminf(fmaxf(q, -128.0f), 127.0f);
    return (int)q;
}
__device__ __forceinline__ float fsigm(float x) {
    return __fdividef(1.0f, 1.0f + __expf(-x));
}
__device__ __forceinline__ float ftanh(float x) {
    return __fdividef(2.0f, 1.0f + __expf(-2.0f * x)) - 1.0f;
}

// One kernel quantizes everything (R8-proven version, at HBM roofline):
//  blocks [0, 2048)        : Xh rows  -> Xhq[m][k] int8, k<1024 from X, else h
//  blocks [2048, 6144)     : W rows   -> Wq[p][k] int8, packed p = j*4 + gate
//  block  6144             : bias     -> bqp[j*4 + gate] (fake-quantized f32)
__global__ __launch_bounds__(256) void quant_pack(
    const float* __restrict__ X, const float* __restrict__ hI,
    const float* __restrict__ W, const float* __restrict__ bias,
    int8_t* __restrict__ Xhq, int8_t* __restrict__ Wq, float* __restrict__ bqp)
{
    const int bid = blockIdx.x;
    const int t = threadIdx.x;
    if (bid < B_DIM) {
        const int m = bid;
        const int k0 = t * 8;
        const float* src = (k0 < 1024) ? (X + (size_t)m * 1024 + k0)
                                       : (hI + (size_t)m * 1024 + (k0 - 1024));
        float4 v0 = *(const float4*)src;
        float4 v1 = *(const float4*)(src + 4);
        union { int8_t c[8]; int64_t ll; } u;
        u.c[0] = (int8_t)q8i(v0.x); u.c[1] = (int8_t)q8i(v0.y);
        u.c[2] = (int8_t)q8i(v0.z); u.c[3] = (int8_t)q8i(v0.w);
        u.c[4] = (int8_t)q8i(v1.x); u.c[5] = (int8_t)q8i(v1.y);
        u.c[6] = (int8_t)q8i(v1.z); u.c[7] = (int8_t)q8i(v1.w);
        *(int64_t*)(Xhq + (size_t)m * K_DIM + k0) = u.ll;
    } else if (bid < B_DIM + N_PACK) {
        const int r = bid - B_DIM;          // original weight row (gate*1024 + j)
        const int gate = r >> 10, j = r & 1023;
        const int p = (j << 2) | gate;      // packed row
        const int k0 = t * 8;
        const float* src = W + (size_t)r * K_DIM + k0;
        float4 v0 = *(const float4*)src;
        float4 v1 = *(const float4*)(src + 4);
        union { int8_t c[8]; int64_t ll; } u;
        u.c[0] = (int8_t)q8i(v0.x); u.c[1] = (int8_t)q8i(v0.y);
        u.c[2] = (int8_t)q8i(v0.z); u.c[3] = (int8_t)q8i(v0.w);
        u.c[4] = (int8_t)q8i(v1.x); u.c[5] = (int8_t)q8i(v1.y);
        u.c[6] = (int8_t)q8i(v1.z); u.c[7] = (int8_t)q8i(v1.w);
        *(int64_t*)(Wq + (size_t)p * K_DIM + k0) = u.ll;
    } else {
        for (int idx = t; idx < N_PACK; idx += 256) {
            const int gate = idx >> 10, j = idx & 1023;
            bqp[(j << 2) | gate] = fqf(bias[idx]);
        }
    }
}

// GEMM C[2048][4096p] = Xhq @ Wq^T (int8 -> i32, exact), fused LSTM epilogue.
// R13: the untested matrix cell = deep prefetch AT 2 blocks/CU.
//   Evidence: all 1-blk/CU configs ~50us GEMM regardless of structure; all
//   2-blk configs ~30us regardless of waves/LDS-volume (R11 did HALF of R8's
//   per-block work in the same time -> per-tile interval is a latency chain,
//   depth-1 prefetch + 2 barriers/tile). Fix the chain, keep 2 blocks/CU.
// Changes vs R8 (everything else identical: 512 thr, 8 waves 2m x 4n of
// 64x32, BM=BN=128, grid 512 + XCD swizzle, 64KB LDS, epilogue):
//   BK=64 (32 K-tiles), 4 LDS slots x 16KB, DEPTH-3 counted prefetch
//   (vmcnt(4): loads consumed 3 intervals after issue), ONE barrier per
//   tile (32 total = R8's count). STAGE placed AFTER the barrier into slot
//   (kt+3)&3 = (kt-1)&3 whose readers finished pre-barrier (R12-proven
//   discipline, absmax=0 there).
// LDS layout (BK=64: 64B/row): row-pair per 128B line; 16B slot s of pair q
//   holds chunk u = s ^ (q&7), u = {h=u>>2: row parity, c=u&3: 16B col}.
//   Frag read lane l (rrow=l&15, g4=l>>4): s = (g4 | (rrow&1)<<2) ^ ((rrow>>1)&7)
//   -> per 16-lane phase each s hit exactly 2x = conflict-free; gll dest
//   stays perfectly linear (t*16), source pre-swizzled (m104 rule).
__global__ __launch_bounds__(512, 4) void lstm_gemm(
    const int8_t* __restrict__ Xhq, const int8_t* __restrict__ Wq,
    const float* __restrict__ bqp, const float* __restrict__ cin,
    float* __restrict__ hout, float* __restrict__ cout_)
{
    __shared__ __align__(16) char raw[65536];   // 4 slots x (A 8K + B 8K); epilogue aliases
    const int t = threadIdx.x;          // 0..511
    const int l = t & 63;
    const int wave = t >> 6;            // 0..7
    const int wm = wave >> 2;           // 0..1  (64 m-rows each)
    const int wn = wave & 3;            // 0..3  (32 packed cols each)

    // XCD-aware remap (R8-proven, bijective for 512 = 8*64)
    const int b = blockIdx.x;
    const int xcd = b & 7;
    const int slot = b >> 3;            // 0..63
    const int mt = ((xcd & 1) << 3) + (slot & 7);    // 0..15
    const int nt = ((xcd >> 1) << 3) + (slot >> 3);  // 0..31
    const int m0 = mt * 128;
    const int n0 = nt * 128;

    v4i acc[4][2];
    #pragma unroll
    for (int i = 0; i < 4; ++i)
        #pragma unroll
        for (int j = 0; j < 2; ++j)
            acc[i][j] = (v4i)0;

    // Staging geometry: thread t -> LDS byte t*16 = (pair rp = t>>3, slot s = t&7).
    // Global chunk u = s ^ (rp&7): row = 2*rp + (u>>2), 16B-col = u&3.
    const int rp_s = t >> 3;                     // 0..63 (row pairs, 128 rows)
    const int u_s = (t & 7) ^ (rp_s & 7);
    const int grow = 2 * rp_s + (u_s >> 2);
    const int gcol = (u_s & 3) * 16;
    const int8_t* gA = Xhq + (size_t)(m0 + grow) * K_DIM + gcol;
    const int8_t* gB = Wq  + (size_t)(n0 + grow) * K_DIM + gcol;

    // slot p: A 8KB at p*16384, B 8KB at +8192. One gll each (512 thr x 16B).
#define STAGE(p, kt) do { \
    __builtin_amdgcn_global_load_lds( \
        (const __attribute__((address_space(1))) uint32_t*)(gA + (size_t)(kt) * 64), \
        (__attribute__((address_space(3))) uint32_t*)(raw + (p) * 16384 + t * 16), 16, 0, 0); \
    __builtin_amdgcn_global_load_lds( \
        (const __attribute__((address_space(1))) uint32_t*)(gB + (size_t)(kt) * 64), \
        (__attribute__((address_space(3))) uint32_t*)(raw + (p) * 16384 + 8192 + t * 16), 16, 0, 0); \
} while (0)

    // Prologue: tiles 0,1,2 in flight (6 loads).
    STAGE(0, 0); STAGE(1, 1); STAGE(2, 2);

    const int rrow = l & 15;
    const int rp = rrow >> 1;                    // fragment row pair 0..7
    const int g4 = l >> 4;                       // 0..3 (16B col within 64B)
    const int soff = (((g4 | ((rrow & 1) << 2)) ^ (rp & 7)) << 4);

#define COMPUTE(kt) do { \
    const char* As_ = raw + ((kt) & 3) * 16384; \
    const char* Bs_ = As_ + 8192; \
    v4i a_[4], b_[2]; \
    _Pragma("unroll") \
    for (int mf = 0; mf < 4; ++mf) \
        a_[mf] = *(const v4i*)(As_ + (wm * 32 + mf * 8 + rp) * 128 + soff); \
    _Pragma("unroll") \
    for (int nf = 0; nf < 2; ++nf) \
        b_[nf] = *(const v4i*)(Bs_ + (wn * 16 + nf * 8 + rp) * 128 + soff); \
    __builtin_amdgcn_s_setprio(1); \
    _Pragma("unroll") \
    for (int mf = 0; mf < 4; ++mf) \
        _Pragma("unroll") \
        for (int nf = 0; nf < 2; ++nf) \
            acc[mf][nf] = __builtin_amdgcn_mfma_i32_16x16x64_i8( \
                a_[mf], b_[nf], acc[mf][nf], 0, 0, 0); \
    __builtin_amdgcn_s_setprio(0); \
} while (0)

    // Main loop kt = 0..28: vmcnt(4) = tiles kt+1,kt+2 in flight, tile kt
    // landed (issued 3 intervals ago). STAGE(kt+3) after the barrier.
    for (int kt = 0; kt < 29; ++kt) {
        asm volatile("s_waitcnt vmcnt(4)" ::: "memory");
        asm volatile("s_barrier" ::: "memory");
        STAGE((kt + 3) & 3, kt + 3);
        COMPUTE(kt);
    }
    // Tail: no more staging. kt=29: tiles 30,31 in flight; 30: tile 31; 31: none.
    asm volatile("s_waitcnt vmcnt(4)" ::: "memory");
    asm volatile("s_barrier" ::: "memory");
    COMPUTE(29);
    asm volatile("s_waitcnt vmcnt(2)" ::: "memory");
    asm volatile("s_barrier" ::: "memory");
    COMPUTE(30);
    asm volatile("s_waitcnt vmcnt(0)" ::: "memory");
    asm volatile("s_barrier" ::: "memory");
    COMPUTE(31);

#undef STAGE
#undef COMPUTE

    // Epilogue (R8-proven verbatim): two 64-row halves through an LDS C-tile.
    float (*Cs)[132] = (float(*)[132])raw;   // [64][132] f32 = 33792 B
    const float sc = 0.0009765625f;          // 2^-10
    for (int half = 0; half < 2; ++half) {
        __syncthreads();
        if (wm == half) {
            #pragma unroll
            for (int mf = 0; mf < 4; ++mf) {
                const int rb = mf * 16 + ((l >> 4) << 2);
                #pragma unroll
                for (int nf = 0; nf < 2; ++nf) {
                    const int col = wn * 32 + nf * 16 + (l & 15);
                    #pragma unroll
                    for (int rr = 0; rr < 4; ++rr)
                        Cs[rb + rr][col] = (float)acc[mf][nf][rr] * sc;
                }
            }
        }
        __syncthreads();
        #pragma unroll
        for (int it = 0; it < 4; ++it) {
            const int idx = it * 512 + t;        // 0..2047 = 64 rows x 32 j
            const int row = idx >> 5;
            const int jl = idx & 31;
            float4 y = *(const float4*)&Cs[row][jl << 2];
            float4 bb = *(const float4*)&bqp[n0 + (jl << 2)];
            const int m = m0 + half * 64 + row;
            const int j = (n0 >> 2) + jl;
            const float ig = fqf(fsigm(y.x + bb.x));
            const float fg = fqf(fsigm(y.y + bb.y));
            const float gg = fqf(ftanh(y.z + bb.z));
            const float og = fqf(fsigm(y.w + bb.w));
            const float cq = fqf(cin[(size_t)m * 1024 + j]);
            const float cn = cq * fg + ig * gg;
            const float hn = fqf(ftanh(cn)) * og;
            hout[(size_t)m * 1024 + j] = hn;
            cout_[(size_t)m * 1024 + j] = cn;
        }
    }
}

extern "C" void kernel_launch(void* const* d_in, const int* in_sizes, int n_in,
                              void* d_out, int out_size, void* d_ws, size_t ws_size,
                              hipStream_t stream) {
    const float* X    = (const float*)d_in[0];   // [2048,1024]
    const float* h    = (const float*)d_in[1];   // [2048,1024]
    const float* c    = (const float*)d_in[2];   // [2048,1024]
    const float* W    = (const float*)d_in[3];   // [4096,2048]
    const float* bias = (const float*)d_in[4];   // [4096]

    float* out   = (float*)d_out;
    float* h_out = out;                          // [2048,1024]
    float* c_out = out + (size_t)B_DIM * 1024;   // [2048,1024]

    char* ws = (char*)d_ws;
    int8_t* Xhq = (int8_t*)ws;                              // 4 MB
    int8_t* Wq  = (int8_t*)(ws + (size_t)4 * 1024 * 1024);  // 8 MB
    float*  bqp = (float*)(ws + (size_t)12 * 1024 * 1024);  // 16 KB

    quant_pack<<<B_DIM + N_PACK + 1, 256, 0, stream>>>(X, h, W, bias, Xhq, Wq, bqp);

    lstm_gemm<<<512, 512, 0, stream>>>(Xhq, Wq, bqp, c, h_out, c_out);
}

// Round 6
// 42.132 us; speedup vs baseline: 1.4279x; 1.0005x over previous
//
#include <hip/hip_runtime.h>
#include <stdint.h>

#define B_DIM 2048
#define K_DIM 2048
#define N_PACK 4096

typedef int v4i __attribute__((ext_vector_type(4)));

__device__ __forceinline__ float fqf(float x) {
    float q = rintf(x * 32.0f);
    q = fminf(fmaxf(q, -128.0f), 127.0f);
    return q * 0.03125f;
}
__device__ __forceinline__ int q8i(float x) {
    float q = rintf(x * 32.0f);
    q = fminf(fmaxf(q, -128.0f), 127.0f);
    return (int)q;
}
__device__ __forceinline__ float fsigm(float x) {
    return __fdividef(1.0f, 1.0f + __expf(-x));
}
__device__ __forceinline__ float ftanh(float x) {
    return __fdividef(2.0f, 1.0f + __expf(-2.0f * x)) - 1.0f;
}

// One kernel quantizes everything (R8-proven version, at HBM roofline):
//  blocks [0, 2048)        : Xh rows  -> Xhq[m][k] int8, k<1024 from X, else h
//  blocks [2048, 6144)     : W rows   -> Wq[p][k] int8, packed p = j*4 + gate
//  block  6144             : bias     -> bqp[j*4 + gate] (fake-quantized f32)
__global__ __launch_bounds__(256) void quant_pack(
    const float* __restrict__ X, const float* __restrict__ hI,
    const float* __restrict__ W, const float* __restrict__ bias,
    int8_t* __restrict__ Xhq, int8_t* __restrict__ Wq, float* __restrict__ bqp)
{
    const int bid = blockIdx.x;
    const int t = threadIdx.x;
    if (bid < B_DIM) {
        const int m = bid;
        const int k0 = t * 8;
        const float* src = (k0 < 1024) ? (X + (size_t)m * 1024 + k0)
                                       : (hI + (size_t)m * 1024 + (k0 - 1024));
        float4 v0 = *(const float4*)src;
        float4 v1 = *(const float4*)(src + 4);
        union { int8_t c[8]; int64_t ll; } u;
        u.c[0] = (int8_t)q8i(v0.x); u.c[1] = (int8_t)q8i(v0.y);
        u.c[2] = (int8_t)q8i(v0.z); u.c[3] = (int8_t)q8i(v0.w);
        u.c[4] = (int8_t)q8i(v1.x); u.c[5] = (int8_t)q8i(v1.y);
        u.c[6] = (int8_t)q8i(v1.z); u.c[7] = (int8_t)q8i(v1.w);
        *(int64_t*)(Xhq + (size_t)m * K_DIM + k0) = u.ll;
    } else if (bid < B_DIM + N_PACK) {
        const int r = bid - B_DIM;          // original weight row (gate*1024 + j)
        const int gate = r >> 10, j = r & 1023;
        const int p = (j << 2) | gate;      // packed row
        const int k0 = t * 8;
        const float* src = W + (size_t)r * K_DIM + k0;
        float4 v0 = *(const float4*)src;
        float4 v1 = *(const float4*)(src + 4);
        union { int8_t c[8]; int64_t ll; } u;
        u.c[0] = (int8_t)q8i(v0.x); u.c[1] = (int8_t)q8i(v0.y);
        u.c[2] = (int8_t)q8i(v0.z); u.c[3] = (int8_t)q8i(v0.w);
        u.c[4] = (int8_t)q8i(v1.x); u.c[5] = (int8_t)q8i(v1.y);
        u.c[6] = (int8_t)q8i(v1.z); u.c[7] = (int8_t)q8i(v1.w);
        *(int64_t*)(Wq + (size_t)p * K_DIM + k0) = u.ll;
    } else {
        for (int idx = t; idx < N_PACK; idx += 256) {
            const int gate = idx >> 10, j = idx & 1023;
            bqp[(j << 2) | gate] = fqf(bias[idx]);
        }
    }
}

// GEMM C[2048][4096p] = Xhq @ Wq^T (int8 -> i32, exact), fused LSTM epilogue.
// R14: cut STAGED BYTES (the measured wall). Six rounds show per-tile time
// tracks staged bytes/CU (~10-11 TB/s chip-wide gll throughput), invariant
// to schedule. Staged total = 4MB*Nt + 8MB*Mt: R8's 512-block configs are
// pinned at 256 MB; BM=256/BN=128 (grid 256) gives 192 MB (-25%). Previous
// 1-blk/CU attempts died on latency at 2 waves/SIMD -> use 1024-THREAD
// blocks: grid 256 = 1 block/CU but 16 waves = 4 waves/SIMD (R8's proven
// latency-hiding density). R13's proven loop: single barrier per tile,
// 3x48KB slots, depth-2 counted vmcnt (never 0 mid-loop), stage-after-
// barrier overwrite discipline (R12-proven race-free, absmax=0).
// Per wave per tile: 16 MFMA (2x R13's cluster) between barriers.
// XCD swizzle: xcd=b&7 owns 4mt x 8nt -> A 2MB + B 2MB = one XCD L2.
// LDS chunk swizzle (proven 0-conflict): LDS[r][s] holds chunk s ^ (r&7),
// via pre-swizzled global source (linear gll dest, m104 rule).
__global__ __launch_bounds__(1024, 1) void lstm_gemm(
    const int8_t* __restrict__ Xhq, const int8_t* __restrict__ Wq,
    const float* __restrict__ bqp, const float* __restrict__ cin,
    float* __restrict__ hout, float* __restrict__ cout_)
{
    __shared__ __align__(16) char raw[147456];  // 3 x (A 32K + B 16K); epilogue aliases
    const int t = threadIdx.x;          // 0..1023
    const int l = t & 63;
    const int wave = t >> 6;            // 0..15
    const int wm = wave >> 2;           // 0..3  (64 m-rows each)
    const int wn = wave & 3;            // 0..3  (32 packed cols each)

    // XCD-aware remap: 256 blocks = 8 xcd x 32 slot (bijective)
    const int b = blockIdx.x;
    const int xcd = b & 7;
    const int slot = b >> 3;            // 0..31
    const int mt = ((xcd & 1) << 2) + (slot & 3);    // 0..7
    const int nt = ((xcd >> 1) << 3) + (slot >> 2);  // 0..31
    const int m0 = mt * 256;
    const int n0 = nt * 128;

    v4i acc[4][2];
    #pragma unroll
    for (int i = 0; i < 4; ++i)
        #pragma unroll
        for (int j = 0; j < 2; ++j)
            acc[i][j] = (v4i)0;

    // staging: thread t covers A rows {srow, srow+128}, B row srow; slot t&7.
    // LDS (r, s) holds global chunk s ^ (r&7); (srow+128)&7 == srow&7.
    const int srow = t >> 3;                      // 0..127
    const int schunk = (t & 7) ^ (srow & 7);
    const int8_t* gA = Xhq + (size_t)(m0 + srow) * K_DIM + schunk * 16;
    const int8_t* gB = Wq  + (size_t)(n0 + srow) * K_DIM + schunk * 16;

    // slot sb: A 32KB (256 rows x 128B) at +0, B 16KB (128 x 128B) at +32768.
    // 3 gll per thread per tile (1024 thr x 16B = 16KB per gll round).
#define STAGE(sb, kt) do { \
    _Pragma("unroll") \
    for (int i_ = 0; i_ < 2; ++i_) \
        __builtin_amdgcn_global_load_lds( \
            (const __attribute__((address_space(1))) uint32_t*)(gA + (size_t)(i_ * 128) * K_DIM + (size_t)(kt) * 128), \
            (__attribute__((address_space(3))) uint32_t*)(raw + (sb) + i_ * 16384 + t * 16), 16, 0, 0); \
    __builtin_amdgcn_global_load_lds( \
        (const __attribute__((address_space(1))) uint32_t*)(gB + (size_t)(kt) * 128), \
        (__attribute__((address_space(3))) uint32_t*)(raw + (sb) + 32768 + t * 16), 16, 0, 0); \
} while (0)

    // Prologue: tiles 0,1 in flight (6 loads).
    STAGE(0, 0); STAGE(49152, 1);

    const int rrow = l & 15;
    const int lx = l & 7;   // == r&7 for all fragment rows
    const int g4 = l >> 4;  // 0..3

    int sC = 0;             // byte base of slot kt%3
    int sN = 98304;         // byte base of slot (kt+2)%3
    for (int kt = 0; kt < 16; ++kt) {
        // Wait: tile kt landed. Outstanding newer = tile kt+1's 3 loads
        // (kt+2 issued after this barrier). Never drained mid-loop.
        if (kt < 15) asm volatile("s_waitcnt vmcnt(3)" ::: "memory");
        else         asm volatile("s_waitcnt vmcnt(0)" ::: "memory");
        asm volatile("s_barrier" ::: "memory");
        // Stage tile kt+2 into slot (kt-1)%3: its readers (iter kt-1) all
        // sampled LDS before barrier(kt) -- race-free (R12-proven).
        if (kt < 14) STAGE(sN, kt + 2);

        const char* As = raw + sC;
        const char* Bs = As + 32768;
        v4i a[2][4], b2[2][2];
        #pragma unroll
        for (int kk = 0; kk < 2; ++kk) {
            const int sl = ((kk * 4 + g4) ^ lx) * 16;
            #pragma unroll
            for (int mf = 0; mf < 4; ++mf)
                a[kk][mf] = *(const v4i*)(As + (wm * 64 + mf * 16 + rrow) * 128 + sl);
            #pragma unroll
            for (int nf = 0; nf < 2; ++nf)
                b2[kk][nf] = *(const v4i*)(Bs + (wn * 32 + nf * 16 + rrow) * 128 + sl);
        }
        __builtin_amdgcn_s_setprio(1);
        #pragma unroll
        for (int kk = 0; kk < 2; ++kk)
            #pragma unroll
            for (int mf = 0; mf < 4; ++mf)
                #pragma unroll
                for (int nf = 0; nf < 2; ++nf)
                    acc[mf][nf] = __builtin_amdgcn_mfma_i32_16x16x64_i8(
                        a[kk][mf], b2[kk][nf], acc[mf][nf], 0, 0, 0);
        __builtin_amdgcn_s_setprio(0);

        sC += 49152; if (sC == 147456) sC = 0;
        sN += 49152; if (sN == 147456) sN = 0;
    }

#undef STAGE

    // Epilogue: four 64-row rounds through an LDS C-tile (aliases staging).
    // Round r rows [m0 + r*64, +64): written by the 4 waves with wm == r.
    float (*Cs)[132] = (float(*)[132])raw;   // [64][132] f32 = 33792 B
    const float sc = 0.0009765625f;          // 2^-10
    for (int r = 0; r < 4; ++r) {
        __syncthreads();
        if (wm == r) {
            #pragma unroll
            for (int mf = 0; mf < 4; ++mf) {
                const int rb = mf * 16 + ((l >> 4) << 2);
                #pragma unroll
                for (int nf = 0; nf < 2; ++nf) {
                    const int col = wn * 32 + nf * 16 + (l & 15);
                    #pragma unroll
                    for (int rr = 0; rr < 4; ++rr)
                        Cs[rb + rr][col] = (float)acc[mf][nf][rr] * sc;
                }
            }
        }
        __syncthreads();
        #pragma unroll
        for (int it = 0; it < 2; ++it) {
            const int idx = it * 1024 + t;       // 0..2047 = 64 rows x 32 j
            const int row = idx >> 5;
            const int jl = idx & 31;
            float4 y = *(const float4*)&Cs[row][jl << 2];
            float4 bb = *(const float4*)&bqp[n0 + (jl << 2)];
            const int m = m0 + r * 64 + row;
            const int j = (n0 >> 2) + jl;
            const float ig = fqf(fsigm(y.x + bb.x));
            const float fg = fqf(fsigm(y.y + bb.y));
            const float gg = fqf(ftanh(y.z + bb.z));
            const float og = fqf(fsigm(y.w + bb.w));
            const float cq = fqf(cin[(size_t)m * 1024 + j]);
            const float cn = cq * fg + ig * gg;
            const float hn = fqf(ftanh(cn)) * og;
            hout[(size_t)m * 1024 + j] = hn;
            cout_[(size_t)m * 1024 + j] = cn;
        }
    }
}

extern "C" void kernel_launch(void* const* d_in, const int* in_sizes, int n_in,
                              void* d_out, int out_size, void* d_ws, size_t ws_size,
                              hipStream_t stream) {
    const float* X    = (const float*)d_in[0];   // [2048,1024]
    const float* h    = (const float*)d_in[1];   // [2048,1024]
    const float* c    = (const float*)d_in[2];   // [2048,1024]
    const float* W    = (const float*)d_in[3];   // [4096,2048]
    const float* bias = (const float*)d_in[4];   // [4096]

    float* out   = (float*)d_out;
    float* h_out = out;                          // [2048,1024]
    float* c_out = out + (size_t)B_DIM * 1024;   // [2048,1024]

    char* ws = (char*)d_ws;
    int8_t* Xhq = (int8_t*)ws;                              // 4 MB
    int8_t* Wq  = (int8_t*)(ws + (size_t)4 * 1024 * 1024);  // 8 MB
    float*  bqp = (float*)(ws + (size_t)12 * 1024 * 1024);  // 16 KB

    quant_pack<<<B_DIM + N_PACK + 1, 256, 0, stream>>>(X, h, W, bias, Xhq, Wq, bqp);

    lstm_gemm<<<256, 1024, 0, stream>>>(Xhq, Wq, bqp, c, h_out, c_out);
}

// Round 7
// 40.719 us; speedup vs baseline: 1.4775x; 1.0347x over previous
//
#include <hip/hip_runtime.h>
#include <stdint.h>

#define B_DIM 2048
#define K_DIM 2048
#define N_PACK 4096

typedef int v4i __attribute__((ext_vector_type(4)));

__device__ __forceinline__ float fqf(float x) {
    float q = rintf(x * 32.0f);
    q = fminf(fmaxf(q, -128.0f), 127.0f);
    return q * 0.03125f;
}
__device__ __forceinline__ int q8i(float x) {
    float q = rintf(x * 32.0f);
    q = fminf(fmaxf(q, -128.0f), 127.0f);
    return (int)q;
}
// fast sigmoid/tanh: v_exp_f32 + fast div; saturate gracefully at +-inf.
__device__ __forceinline__ float fsigm(float x) {
    return __fdividef(1.0f, 1.0f + __expf(-x));
}
__device__ __forceinline__ float ftanh(float x) {
    return __fdividef(2.0f, 1.0f + __expf(-2.0f * x)) - 1.0f;
}

// One kernel quantizes everything. R15: 16 elements/thread -> 16B/lane
// stores (full-width coalescing; was 8B), half the store instructions,
// half the blocks. Same arithmetic, same bytes, exact same outputs.
//  blocks [0, 1024)        : Xh rows 2b,2b+1 -> Xhq[m][k] int8 (k<1024 X, else h)
//  blocks [1024, 3072)     : W rows         -> Wq[p][k] int8, packed p = j*4 + gate
//  block  3072             : bias           -> bqp[j*4 + gate] (fake-quantized f32)
__global__ __launch_bounds__(256) void quant_pack(
    const float* __restrict__ X, const float* __restrict__ hI,
    const float* __restrict__ W, const float* __restrict__ bias,
    int8_t* __restrict__ Xhq, int8_t* __restrict__ Wq, float* __restrict__ bqp)
{
    const int bid = blockIdx.x;
    const int t = threadIdx.x;
    if (bid < 1024) {
        const int m = bid * 2 + (t >> 7);        // 2 rows per block
        const int k0 = (t & 127) * 16;           // 1024%16==0: never straddles X/h
        const float* src = (k0 < 1024) ? (X + (size_t)m * 1024 + k0)
                                       : (hI + (size_t)m * 1024 + (k0 - 1024));
        float4 v0 = *(const float4*)src;
        float4 v1 = *(const float4*)(src + 4);
        float4 v2 = *(const float4*)(src + 8);
        float4 v3 = *(const float4*)(src + 12);
        union { int8_t c[16]; v4i q; } u;
        u.c[0]  = (int8_t)q8i(v0.x); u.c[1]  = (int8_t)q8i(v0.y);
        u.c[2]  = (int8_t)q8i(v0.z); u.c[3]  = (int8_t)q8i(v0.w);
        u.c[4]  = (int8_t)q8i(v1.x); u.c[5]  = (int8_t)q8i(v1.y);
        u.c[6]  = (int8_t)q8i(v1.z); u.c[7]  = (int8_t)q8i(v1.w);
        u.c[8]  = (int8_t)q8i(v2.x); u.c[9]  = (int8_t)q8i(v2.y);
        u.c[10] = (int8_t)q8i(v2.z); u.c[11] = (int8_t)q8i(v2.w);
        u.c[12] = (int8_t)q8i(v3.x); u.c[13] = (int8_t)q8i(v3.y);
        u.c[14] = (int8_t)q8i(v3.z); u.c[15] = (int8_t)q8i(v3.w);
        *(v4i*)(Xhq + (size_t)m * K_DIM + k0) = u.q;
    } else if (bid < 3072) {
        const int r = (bid - 1024) * 2 + (t >> 7);  // original weight row (gate*1024 + j)
        const int gate = r >> 10, j = r & 1023;
        const int p = (j << 2) | gate;              // packed row
        const int k0 = (t & 127) * 16;
        const float* src = W + (size_t)r * K_DIM + k0;
        float4 v0 = *(const float4*)src;
        float4 v1 = *(const float4*)(src + 4);
        float4 v2 = *(const float4*)(src + 8);
        float4 v3 = *(const float4*)(src + 12);
        union { int8_t c[16]; v4i q; } u;
        u.c[0]  = (int8_t)q8i(v0.x); u.c[1]  = (int8_t)q8i(v0.y);
        u.c[2]  = (int8_t)q8i(v0.z); u.c[3]  = (int8_t)q8i(v0.w);
        u.c[4]  = (int8_t)q8i(v1.x); u.c[5]  = (int8_t)q8i(v1.y);
        u.c[6]  = (int8_t)q8i(v1.z); u.c[7]  = (int8_t)q8i(v1.w);
        u.c[8]  = (int8_t)q8i(v2.x); u.c[9]  = (int8_t)q8i(v2.y);
        u.c[10] = (int8_t)q8i(v2.z); u.c[11] = (int8_t)q8i(v2.w);
        u.c[12] = (int8_t)q8i(v3.x); u.c[13] = (int8_t)q8i(v3.y);
        u.c[14] = (int8_t)q8i(v3.z); u.c[15] = (int8_t)q8i(v3.w);
        *(v4i*)(Wq + (size_t)p * K_DIM + k0) = u.q;
    } else {
        for (int idx = t; idx < N_PACK; idx += 256) {
            const int gate = idx >> 10, j = idx & 1023;
            bqp[(j << 2) | gate] = fqf(bias[idx]);
        }
    }
}

// GEMM C[2048][4096p] = Xhq @ Wq^T (int8 -> i32, exact), fused LSTM epilogue.
// R15 = R8 VERBATIM (session-best 41.08 us). Seven configs proved the GEMM
// interval invariant to staged bytes / LDS bytes / barriers / depth / tile
// shape, requiring only >=2 schedulable entities per SIMD — R8 satisfies
// that with 2 blocks/CU and is the measured optimum of the family.
// 1-D grid of 512; block b -> xcd = b%8 (HW round-robin), slot = b/8 (0..63);
// each XCD owns an 8x8 (m,n) sub-grid: mt = (xcd&1)*8 + (slot&7),
// nt = (xcd>>1)*8 + (slot>>3). Working set per XCD-L2 = 8 A-panels (2MB) +
// 8 B-panels (2MB) = 4MB = one XCD L2 -> staging streams from warm L2.
// LDS chunk swizzle (proven 0-conflict): LDS[r][s] holds chunk s ^ (r&7).
__global__ __launch_bounds__(512) void lstm_gemm(
    const int8_t* __restrict__ Xhq, const int8_t* __restrict__ Wq,
    const float* __restrict__ bqp, const float* __restrict__ cin,
    float* __restrict__ hout, float* __restrict__ cout_)
{
    __shared__ __align__(16) char raw[65536];   // 2 x (A 16K + B 16K); epilogue aliases
    const int t = threadIdx.x;          // 0..511
    const int l = t & 63;
    const int wave = t >> 6;            // 0..7
    const int wm = wave >> 2;           // 0..1  (64 m-rows each)
    const int wn = wave & 3;            // 0..3  (32 packed cols each)

    const int b = blockIdx.x;
    const int xcd = b & 7;
    const int slot = b >> 3;            // 0..63
    const int mt = ((xcd & 1) << 3) + (slot & 7);    // 0..15
    const int nt = ((xcd >> 1) << 3) + (slot >> 3);  // 0..31
    const int m0 = mt * 128;
    const int n0 = nt * 128;

    v4i acc[4][2];
    #pragma unroll
    for (int i = 0; i < 4; ++i)
        #pragma unroll
        for (int j = 0; j < 2; ++j)
            acc[i][j] = (v4i)0;

    // staging: thread t covers rows {srow, srow+64}, slot t&7.
    // LDS slot (r, s) holds global chunk s ^ (r&7); (srow+64)&7 == srow&7.
    const int srow = t >> 3;                      // 0..63
    const int schunk = (t & 7) ^ (srow & 7);
    const int8_t* gA = Xhq + (size_t)(m0 + srow) * K_DIM + schunk * 16;
    const int8_t* gB = Wq  + (size_t)(n0 + srow) * K_DIM + schunk * 16;

    const int rrow = l & 15;
    const int lx = l & 7;   // == r&7 for all fragment rows

#define STAGE(p, kt) do { \
    char* Ad_ = raw + (p) * 32768; \
    char* Bd_ = raw + (p) * 32768 + 16384; \
    _Pragma("unroll") \
    for (int i_ = 0; i_ < 2; ++i_) { \
        __builtin_amdgcn_global_load_lds( \
            (const __attribute__((address_space(1))) uint32_t*)(gA + (size_t)(i_ * 64) * K_DIM + (kt) * 128), \
            (__attribute__((address_space(3))) uint32_t*)(Ad_ + i_ * 8192 + t * 16), 16, 0, 0); \
        __builtin_amdgcn_global_load_lds( \
            (const __attribute__((address_space(1))) uint32_t*)(gB + (size_t)(i_ * 64) * K_DIM + (kt) * 128), \
            (__attribute__((address_space(3))) uint32_t*)(Bd_ + i_ * 8192 + t * 16), 16, 0, 0); \
    } \
} while (0)

    STAGE(0, 0);

    for (int kt = 0; kt < 16; ++kt) {
        const int p = kt & 1;
        if (kt < 15) {
            STAGE(p ^ 1, kt + 1);
            asm volatile("s_waitcnt vmcnt(4)" ::: "memory");  // tile kt landed; kt+1 in flight
        } else {
            asm volatile("s_waitcnt vmcnt(0)" ::: "memory");
        }
        asm volatile("s_barrier" ::: "memory");

        const char* As = raw + p * 32768;
        const char* Bs = raw + p * 32768 + 16384;
        v4i a[2][4], b2[2][2];
        #pragma unroll
        for (int kk = 0; kk < 2; ++kk) {
            const int c = kk * 4 + (l >> 4);
            const int sl = (c ^ lx) * 16;
            #pragma unroll
            for (int mf = 0; mf < 4; ++mf) {
                const int r = wm * 64 + mf * 16 + rrow;
                a[kk][mf] = *(const v4i*)(As + r * 128 + sl);
            }
            #pragma unroll
            for (int nf = 0; nf < 2; ++nf) {
                const int r = wn * 32 + nf * 16 + rrow;
                b2[kk][nf] = *(const v4i*)(Bs + r * 128 + sl);
            }
        }
        #pragma unroll
        for (int kk = 0; kk < 2; ++kk)
            #pragma unroll
            for (int mf = 0; mf < 4; ++mf)
                #pragma unroll
                for (int nf = 0; nf < 2; ++nf)
                    acc[mf][nf] = __builtin_amdgcn_mfma_i32_16x16x64_i8(a[kk][mf], b2[kk][nf], acc[mf][nf], 0, 0, 0);
        asm volatile("s_waitcnt lgkmcnt(0)" ::: "memory");   // LDS reads done before overwrite
        asm volatile("s_barrier" ::: "memory");
    }

    // Epilogue: two 64-row halves through an LDS C-tile (aliases staging bufs).
    float (*Cs)[132] = (float(*)[132])raw;   // [64][132] f32 = 33792 B
    const float sc = 0.0009765625f;          // 2^-10
    for (int half = 0; half < 2; ++half) {
        __syncthreads();
        if (wm == half) {
            #pragma unroll
            for (int mf = 0; mf < 4; ++mf) {
                const int rb = mf * 16 + ((l >> 4) << 2);
                #pragma unroll
                for (int nf = 0; nf < 2; ++nf) {
                    const int col = wn * 32 + nf * 16 + (l & 15);
                    #pragma unroll
                    for (int rr = 0; rr < 4; ++rr)
                        Cs[rb + rr][col] = (float)acc[mf][nf][rr] * sc;
                }
            }
        }
        __syncthreads();
        #pragma unroll
        for (int it = 0; it < 4; ++it) {
            const int idx = it * 512 + t;        // 0..2047 = 64 rows x 32 j
            const int row = idx >> 5;
            const int jl = idx & 31;
            float4 y = *(const float4*)&Cs[row][jl << 2];
            float4 bb = *(const float4*)&bqp[n0 + (jl << 2)];
            const int m = m0 + half * 64 + row;
            const int j = (n0 >> 2) + jl;
            const float ig = fqf(fsigm(y.x + bb.x));
            const float fg = fqf(fsigm(y.y + bb.y));
            const float gg = fqf(ftanh(y.z + bb.z));
            const float og = fqf(fsigm(y.w + bb.w));
            const float cq = fqf(cin[(size_t)m * 1024 + j]);
            const float cn = cq * fg + ig * gg;
            const float hn = fqf(ftanh(cn)) * og;
            hout[(size_t)m * 1024 + j] = hn;
            cout_[(size_t)m * 1024 + j] = cn;
        }
    }
}

extern "C" void kernel_launch(void* const* d_in, const int* in_sizes, int n_in,
                              void* d_out, int out_size, void* d_ws, size_t ws_size,
                              hipStream_t stream) {
    const float* X    = (const float*)d_in[0];   // [2048,1024]
    const float* h    = (const float*)d_in[1];   // [2048,1024]
    const float* c    = (const float*)d_in[2];   // [2048,1024]
    const float* W    = (const float*)d_in[3];   // [4096,2048]
    const float* bias = (const float*)d_in[4];   // [4096]

    float* out   = (float*)d_out;
    float* h_out = out;                          // [2048,1024]
    float* c_out = out + (size_t)B_DIM * 1024;   // [2048,1024]

    char* ws = (char*)d_ws;
    int8_t* Xhq = (int8_t*)ws;                              // 4 MB
    int8_t* Wq  = (int8_t*)(ws + (size_t)4 * 1024 * 1024);  // 8 MB
    float*  bqp = (float*)(ws + (size_t)12 * 1024 * 1024);  // 16 KB

    quant_pack<<<3073, 256, 0, stream>>>(X, h, W, bias, Xhq, Wq, bqp);

    lstm_gemm<<<512, 512, 0, stream>>>(Xhq, Wq, bqp, c, h_out, c_out);
}